// Round 1
// baseline (1434.950 us; speedup 1.0000x reference)
//
#include <hip/hip_runtime.h>
#include <hip/hip_bf16.h>

typedef __bf16 bf16;
typedef bf16 bf16x4 __attribute__((ext_vector_type(4)));
typedef bf16 bf16x8 __attribute__((ext_vector_type(8)));
typedef float f32x4 __attribute__((ext_vector_type(4)));

#define GLDS(g, l)                                                            \
  __builtin_amdgcn_global_load_lds(                                           \
      (const __attribute__((address_space(1))) void*)(g),                     \
      (__attribute__((address_space(3))) void*)(l), 16, 0, 0)

constexpr int DM = 3584;
constexpr int NH = 112;
constexpr int HD = 64;
constexpr int DSTATE = 64;
constexpr int CH = 256;
constexpr int NG = 2;
constexpr int SEQ = 4096;
constexpr int INNER = NH * HD;    // 7168
constexpr int NCHUNK = SEQ / CH;  // 16
constexpr int HPG = NH / NG;      // 56

__device__ __forceinline__ float softplus_f(float x) {
  return x > 15.f ? x : log1pf(expf(x));
}

__device__ __forceinline__ f32x4 mfma_bf16(bf16x8 a, bf16x8 b, f32x4 c) {
  return __builtin_amdgcn_mfma_f32_16x16x32_bf16(a, b, c, 0, 0, 0);
}

// ---------------- f32 -> bf16 convert (n multiple of 4) ----------------
__global__ __launch_bounds__(256) void k_cvt(const float* __restrict__ in,
                                             bf16* __restrict__ out, int n4) {
  int i = blockIdx.x * 256 + threadIdx.x;
  if (i >= n4) return;
  float4 v = reinterpret_cast<const float4*>(in)[i];
  bf16x4 o;
  o[0] = (bf16)v.x; o[1] = (bf16)v.y; o[2] = (bf16)v.z; o[3] = (bf16)v.w;
  reinterpret_cast<bf16x4*>(out)[i] = o;
}

// ---------------- m97-style bf16 GEMM, C[m,n] = sum_k A[m,k]*B[n,k] ----
// MODE 0: store bf16 transposed out[n*SEQ + m]        (x -> xT buffer)
// MODE 1: store bf16 natural    out[m*INNER + n]      (z buffer)
// MODE 2: store f32  natural    out[m*DM + n]         (final output)
template <int MODE>
__global__ __launch_bounds__(256) void k_gemm(const bf16* __restrict__ A,
                                              const bf16* __restrict__ B,
                                              void* __restrict__ outp, int K) {
  __shared__ alignas(16) bf16 As[128 * 32];
  __shared__ alignas(16) bf16 Bs[128 * 32];
  const int t = threadIdx.x;
  const int wave = t >> 6, lane = t & 63;
  const int quad = lane >> 4, l16 = lane & 15;
  const int wm = (wave >> 1) * 64, wn = (wave & 1) * 64;
  const long m0 = (long)blockIdx.y * 128, n0 = (long)blockIdx.x * 128;

  const int r_s = t >> 2, c_s = (t & 3) * 8;  // staging row / col8
  const bf16* gA = A + (m0 + r_s) * (long)K + c_s;
  const bf16* gB = B + (n0 + r_s) * (long)K + c_s;
  const long rowstep = (long)64 * K;

  f32x4 acc[4][4] = {};

  for (int k0 = 0; k0 < K; k0 += 32) {
    __syncthreads();
    GLDS(gA, &As[t * 8]);
    GLDS(gA + rowstep, &As[(t + 256) * 8]);
    GLDS(gB, &Bs[t * 8]);
    GLDS(gB + rowstep, &Bs[(t + 256) * 8]);
    gA += 32; gB += 32;
    __syncthreads();
    bf16x8 af[4], bfr[4];
#pragma unroll
    for (int i = 0; i < 4; i++)
      af[i] = *reinterpret_cast<const bf16x8*>(&As[(wm + i * 16 + l16) * 32 + quad * 8]);
#pragma unroll
    for (int j = 0; j < 4; j++)
      bfr[j] = *reinterpret_cast<const bf16x8*>(&Bs[(wn + j * 16 + l16) * 32 + quad * 8]);
#pragma unroll
    for (int i = 0; i < 4; i++)
#pragma unroll
      for (int j = 0; j < 4; j++)
        acc[i][j] = mfma_bf16(af[i], bfr[j], acc[i][j]);
  }

#pragma unroll
  for (int i = 0; i < 4; i++)
#pragma unroll
    for (int j = 0; j < 4; j++) {
      long col = n0 + wn + j * 16 + l16;
      long mg = m0 + wm + i * 16 + quad * 4;
      if constexpr (MODE == 0) {
        bf16* o = (bf16*)outp;
        bf16x4 v;
#pragma unroll
        for (int u = 0; u < 4; u++) v[u] = (bf16)acc[i][j][u];
        *reinterpret_cast<bf16x4*>(&o[col * SEQ + mg]) = v;
      } else if constexpr (MODE == 1) {
        bf16* o = (bf16*)outp;
#pragma unroll
        for (int u = 0; u < 4; u++) o[(mg + u) * (long)INNER + col] = (bf16)acc[i][j][u];
      } else {
        float* o = (float*)outp;
#pragma unroll
        for (int u = 0; u < 4; u++) o[(mg + u) * (long)DM + col] = acc[i][j][u];
      }
    }
}

// ---------------- per-(chunk,head) end-state: states[p,n] -------------
// states = dts * sum_j x[j,p] * B[j,n] * exp(dAh*(255-j))
__global__ __launch_bounds__(256) void k_states(const bf16* __restrict__ xT,
                                                const bf16* __restrict__ Bbf,
                                                const float* __restrict__ A_log,
                                                const float* __restrict__ dt_bias,
                                                float* __restrict__ states) {
  const int kc = blockIdx.x;
  const int h = blockIdx.y;
  const int g = h / HPG;
  const int t = threadIdx.x;
  const int wave = t >> 6, lane = t & 63, quad = lane >> 4, l16 = lane & 15;
  const float dts = softplus_f(0.1f + dt_bias[h]);
  const float dAh = -expf(A_log[h]) * dts;

  __shared__ alignas(16) bf16 xTs[64 * 136];
  __shared__ alignas(16) bf16 BTs[64 * 136];

  const bf16* srcX = xT + (size_t)h * 64 * SEQ + (size_t)kc * CH;
  const bf16* srcB = Bbf + ((size_t)kc * CH * NG + g) * DSTATE;

  f32x4 acc[4] = {};

  for (int half = 0; half < 2; half++) {
    __syncthreads();
    // x^T tile [p][128 j], contiguous rows from xT
#pragma unroll
    for (int q = 0; q < 4; q++) {
      int u = q * 256 + t;
      int row = u >> 4, c8 = (u & 15) * 8;
      bf16x8 v = *reinterpret_cast<const bf16x8*>(&srcX[(size_t)row * SEQ + half * 128 + c8]);
      *reinterpret_cast<bf16x8*>(&xTs[row * 136 + c8]) = v;
    }
    // B^T tile [n][128 j] with decay scale folded in
#pragma unroll
    for (int q = 0; q < 4; q++) {
      int u = q * 256 + t;
      int jl = u & 127, n8 = (u >> 7) * 8;
      int j = half * 128 + jl;
      bf16x8 v = *reinterpret_cast<const bf16x8*>(&srcB[(size_t)j * (NG * DSTATE) + n8]);
      float s = expf(dAh * (float)(CH - 1 - j));
#pragma unroll
      for (int e = 0; e < 8; e++)
        BTs[(n8 + e) * 136 + jl] = (bf16)((float)v[e] * s);
    }
    __syncthreads();
#pragma unroll
    for (int kk = 0; kk < 4; kk++) {
      bf16x8 a = *reinterpret_cast<const bf16x8*>(&xTs[(wave * 16 + l16) * 136 + kk * 32 + quad * 8]);
#pragma unroll
      for (int tn = 0; tn < 4; tn++) {
        bf16x8 b = *reinterpret_cast<const bf16x8*>(&BTs[(tn * 16 + l16) * 136 + kk * 32 + quad * 8]);
        acc[tn] = mfma_bf16(a, b, acc[tn]);
      }
    }
  }
  float* dst = states + (size_t)(kc * NH + h) * 64 * 64;
#pragma unroll
  for (int tn = 0; tn < 4; tn++)
#pragma unroll
    for (int u = 0; u < 4; u++) {
      int p = wave * 16 + quad * 4 + u;
      dst[p * 64 + tn * 16 + l16] = acc[tn][u] * dts;
    }
}

// ---------------- inter-chunk scan, in place: states[k] <- entering state
__global__ __launch_bounds__(256) void k_scan(float* __restrict__ states,
                                              const float* __restrict__ A_log,
                                              const float* __restrict__ dt_bias) {
  int idx = blockIdx.x * 256 + threadIdx.x;  // NH*4096 total
  int h = idx >> 12;
  int pn = idx & 4095;
  float dts = softplus_f(0.1f + dt_bias[h]);
  float dAh = -expf(A_log[h]) * dts;
  float cd = expf(dAh * (float)CH);
  float carry = 0.f;
  float* p = states + (size_t)h * 4096 + pn;
  const size_t stride = (size_t)NH * 4096;
#pragma unroll
  for (int k = 0; k < NCHUNK; k++) {
    float s = p[k * stride];
    p[k * stride] = carry;
    carry = carry * cd + s;
  }
}

// ---------------- per-(h,chunk,half) output: Y = (S.L).x + C.prev^T + D*x, gated
__global__ __launch_bounds__(256) void k_y(const bf16* __restrict__ xT,
                                           const bf16* __restrict__ Bbf,
                                           const bf16* __restrict__ Cbf,
                                           const float* __restrict__ prev,
                                           bf16* __restrict__ zy,  // in: z, out: y
                                           const float* __restrict__ A_log,
                                           const float* __restrict__ Dvec,
                                           const float* __restrict__ dt_bias) {
  const int half = blockIdx.x;
  const int kc = blockIdx.y;
  const int h = blockIdx.z;
  const int g = h / HPG;
  const int i0 = half * 128;
  const int t = threadIdx.x;
  const int wave = t >> 6, lane = t & 63, quad = lane >> 4, l16 = lane & 15;
  const float dts = softplus_f(0.1f + dt_bias[h]);
  const float dAh = -expf(A_log[h]) * dts;
  const float Dh = Dvec[h];

  __shared__ alignas(16) bf16 Cs[128 * 72];
  __shared__ alignas(16) bf16 Bsh[64 * 72];  // B panel; also holds prev first
  __shared__ alignas(16) bf16 xTs[64 * 72];
  __shared__ alignas(16) bf16 Ws[128 * 72];

  {  // stage C rows [i0..i0+128)
    const bf16* src = Cbf + ((size_t)(kc * CH + i0) * NG + g) * DSTATE;
#pragma unroll
    for (int q = 0; q < 4; q++) {
      int u = q * 256 + t;
      int row = u >> 3, c8 = (u & 7) * 8;
      bf16x8 v = *reinterpret_cast<const bf16x8*>(&src[(size_t)row * (NG * DSTATE) + c8]);
      *reinterpret_cast<bf16x8*>(&Cs[row * 72 + c8]) = v;
    }
  }
  {  // stage prev [p][n] -> bf16 into Bsh
    const float* src = prev + (size_t)(kc * NH + h) * 4096;
#pragma unroll
    for (int q = 0; q < 4; q++) {
      int u = q * 256 + t;
      int p = u >> 4, c4 = (u & 15) * 4;
      float4 v = *reinterpret_cast<const float4*>(&src[p * 64 + c4]);
      bf16x4 o;
      o[0] = (bf16)v.x; o[1] = (bf16)v.y; o[2] = (bf16)v.z; o[3] = (bf16)v.w;
      *reinterpret_cast<bf16x4*>(&Bsh[p * 72 + c4]) = o;
    }
  }
  __syncthreads();

  f32x4 accY[2][4] = {};
  // Y_off = C . prev^T   (K = n-state)
#pragma unroll
  for (int kk = 0; kk < 2; kk++) {
    bf16x8 a0 = *reinterpret_cast<const bf16x8*>(&Cs[(wave * 32 + l16) * 72 + kk * 32 + quad * 8]);
    bf16x8 a1 = *reinterpret_cast<const bf16x8*>(&Cs[(wave * 32 + 16 + l16) * 72 + kk * 32 + quad * 8]);
#pragma unroll
    for (int tn = 0; tn < 4; tn++) {
      bf16x8 b = *reinterpret_cast<const bf16x8*>(&Bsh[(tn * 16 + l16) * 72 + kk * 32 + quad * 8]);
      accY[0][tn] = mfma_bf16(a0, b, accY[0][tn]);
      accY[1][tn] = mfma_bf16(a1, b, accY[1][tn]);
    }
  }
  // scale Y_off by exp(dAh*(i+1))
#pragma unroll
  for (int tm = 0; tm < 2; tm++)
#pragma unroll
    for (int u = 0; u < 4; u++) {
      float sc = expf(dAh * (float)(i0 + wave * 32 + tm * 16 + quad * 4 + u + 1));
#pragma unroll
      for (int tn = 0; tn < 4; tn++) accY[tm][tn][u] *= sc;
    }

  const int npan = half ? 4 : 2;  // skip all-masked panels
  for (int jb = 0; jb < npan; jb++) {
    __syncthreads();
    {  // stage B panel rows j in [jb*64, jb*64+64)
      const bf16* src = Bbf + ((size_t)(kc * CH + jb * 64) * NG + g) * DSTATE;
#pragma unroll
      for (int q = 0; q < 2; q++) {
        int u = q * 256 + t;
        int row = u >> 3, c8 = (u & 7) * 8;
        bf16x8 v = *reinterpret_cast<const bf16x8*>(&src[(size_t)row * (NG * DSTATE) + c8]);
        *reinterpret_cast<bf16x8*>(&Bsh[row * 72 + c8]) = v;
      }
    }
    {  // stage x^T panel [p][64 j]
      const bf16* src = xT + (size_t)h * 64 * SEQ + (size_t)kc * CH + jb * 64;
#pragma unroll
      for (int q = 0; q < 2; q++) {
        int u = q * 256 + t;
        int row = u >> 3, c8 = (u & 7) * 8;
        bf16x8 v = *reinterpret_cast<const bf16x8*>(&src[(size_t)row * SEQ + c8]);
        *reinterpret_cast<bf16x8*>(&xTs[row * 72 + c8]) = v;
      }
    }
    __syncthreads();
    // S = C . B^T (K = n-state)
    f32x4 accS[2][4] = {};
#pragma unroll
    for (int kk = 0; kk < 2; kk++) {
      bf16x8 a0 = *reinterpret_cast<const bf16x8*>(&Cs[(wave * 32 + l16) * 72 + kk * 32 + quad * 8]);
      bf16x8 a1 = *reinterpret_cast<const bf16x8*>(&Cs[(wave * 32 + 16 + l16) * 72 + kk * 32 + quad * 8]);
#pragma unroll
      for (int tj = 0; tj < 4; tj++) {
        bf16x8 b = *reinterpret_cast<const bf16x8*>(&Bsh[(tj * 16 + l16) * 72 + kk * 32 + quad * 8]);
        accS[0][tj] = mfma_bf16(a0, b, accS[0][tj]);
        accS[1][tj] = mfma_bf16(a1, b, accS[1][tj]);
      }
    }
    // W = S .* (dts * r^(i-j), i>=j) -> LDS (per-wave-private rows)
#pragma unroll
    for (int tm = 0; tm < 2; tm++)
#pragma unroll
      for (int tj = 0; tj < 4; tj++)
#pragma unroll
        for (int u = 0; u < 4; u++) {
          int li = wave * 32 + tm * 16 + quad * 4 + u;
          int ai = i0 + li;
          int aj = jb * 64 + tj * 16 + l16;
          float s = (ai >= aj) ? dts * expf(dAh * (float)(ai - aj)) : 0.f;
          Ws[li * 72 + tj * 16 + l16] = (bf16)(accS[tm][tj][u] * s);
        }
    // Y += W . x   (K = j)
#pragma unroll
    for (int kk = 0; kk < 2; kk++) {
      bf16x8 a0 = *reinterpret_cast<const bf16x8*>(&Ws[(wave * 32 + l16) * 72 + kk * 32 + quad * 8]);
      bf16x8 a1 = *reinterpret_cast<const bf16x8*>(&Ws[(wave * 32 + 16 + l16) * 72 + kk * 32 + quad * 8]);
#pragma unroll
      for (int tn = 0; tn < 4; tn++) {
        bf16x8 b = *reinterpret_cast<const bf16x8*>(&xTs[(tn * 16 + l16) * 72 + kk * 32 + quad * 8]);
        accY[0][tn] = mfma_bf16(a0, b, accY[0][tn]);
        accY[1][tn] = mfma_bf16(a1, b, accY[1][tn]);
      }
    }
  }

  // epilogue: + D*x, gate with sigmoid(z), write y in place over z
#pragma unroll
  for (int tm = 0; tm < 2; tm++)
#pragma unroll
    for (int tn = 0; tn < 4; tn++)
#pragma unroll
      for (int u = 0; u < 4; u++) {
        int li = wave * 32 + tm * 16 + quad * 4 + u;
        long lg = (long)kc * CH + i0 + li;
        int p = tn * 16 + l16;
        float xv = (float)xT[(size_t)(h * 64 + p) * SEQ + lg];
        float yv = accY[tm][tn][u] + xv * Dh;
        size_t off = (size_t)lg * INNER + h * 64 + p;
        float zv = (float)zy[off];
        float gate = 1.f / (1.f + expf(-zv));
        zy[off] = (bf16)(yv * gate);
      }
}

extern "C" void kernel_launch(void* const* d_in, const int* in_sizes, int n_in,
                              void* d_out, int out_size, void* d_ws, size_t ws_size,
                              hipStream_t stream) {
  const float* hs    = (const float*)d_in[0];
  const float* W_in  = (const float*)d_in[1];
  const float* W_out = (const float*)d_in[2];
  const float* A_log = (const float*)d_in[3];
  const float* Dv    = (const float*)d_in[4];
  const float* dtb   = (const float*)d_in[5];
  const float* Bin   = (const float*)d_in[6];
  const float* Cin   = (const float*)d_in[7];

  char* ws = (char*)d_ws;
  size_t off = 0;
  auto alloc = [&](size_t bytes) {
    void* p = ws + off;
    off += (bytes + 255) & ~(size_t)255;
    return p;
  };
  bf16* wbuf = (bf16*)alloc((size_t)INNER * DM * 2);        // reused: Win half0, half1, Wout
  bf16* hsb  = (bf16*)alloc((size_t)SEQ * DM * 2);
  bf16* xTg  = (bf16*)alloc((size_t)INNER * SEQ * 2);       // x transposed [h*p][L]
  bf16* zy   = (bf16*)alloc((size_t)SEQ * INNER * 2);       // z, overwritten by y
  bf16* Bbf  = (bf16*)alloc((size_t)SEQ * NG * DSTATE * 2);
  bf16* Cbf  = (bf16*)alloc((size_t)SEQ * NG * DSTATE * 2);
  float* st  = (float*)alloc((size_t)NCHUNK * NH * 64 * 64 * 4);

  auto cvt = [&](const float* src, bf16* dst, size_t n) {
    int n4 = (int)(n / 4);
    k_cvt<<<dim3((n4 + 255) / 256), dim3(256), 0, stream>>>(src, dst, n4);
  };

  cvt(hs, hsb, (size_t)SEQ * DM);
  cvt(Bin, Bbf, (size_t)SEQ * NG * DSTATE);
  cvt(Cin, Cbf, (size_t)SEQ * NG * DSTATE);

  dim3 blk(256);
  dim3 g1(INNER / 128, SEQ / 128);  // 56 x 32

  // GEMM1 half 0 (x) -> transposed store
  cvt(W_in, wbuf, (size_t)INNER * DM);
  k_gemm<0><<<g1, blk, 0, stream>>>(hsb, wbuf, xTg, DM);
  // GEMM1 half 1 (z) -> natural store
  cvt(W_in + (size_t)INNER * DM, wbuf, (size_t)INNER * DM);
  k_gemm<1><<<g1, blk, 0, stream>>>(hsb, wbuf, zy, DM);
  // W_out conversion (wbuf free after GEMM1)
  cvt(W_out, wbuf, (size_t)DM * INNER);

  k_states<<<dim3(NCHUNK, NH), blk, 0, stream>>>(xTg, Bbf, A_log, dtb, st);
  k_scan<<<dim3((NH * 4096) / 256), blk, 0, stream>>>(st, A_log, dtb);
  k_y<<<dim3(2, NCHUNK, NH), blk, 0, stream>>>(xTg, Bbf, Cbf, st, zy, A_log, Dv, dtb);

  dim3 g2(DM / 128, SEQ / 128);  // 28 x 32
  k_gemm<2><<<g2, blk, 0, stream>>>(zy, wbuf, d_out, INNER);

  (void)in_sizes; (void)n_in; (void)out_size; (void)ws_size;
}